// Round 2
// baseline (3164.236 us; speedup 1.0000x reference)
//
#include <hip/hip_runtime.h>

#define N_NODES 50000
#define F_IN    128
#define HEADS   10
#define DH      8
#define H1      80      // HEADS*DH
#define FOUT    16
#define E_IN    800000
#define E_TOT   850000  // + N self loops

__device__ __forceinline__ float lrelu(float v) { return v > 0.f ? v : 0.2f * v; }

// float atomic max via int/uint atomics (valid for all finite floats + -inf init)
__device__ __forceinline__ void atomicMaxF(float* addr, float v) {
    if (v >= 0.f) atomicMax((int*)addr, __float_as_int(v));
    else          atomicMin((unsigned int*)addr, __float_as_uint(v));
}

// ---- init: m=-inf, denoms/accums = 0 ------------------------------------
__global__ void k_init(float* __restrict__ m1, float* __restrict__ dn1,
                       float* __restrict__ acc1, float* __restrict__ m2,
                       float* __restrict__ dn2, float* __restrict__ out) {
    int i = blockIdx.x * blockDim.x + threadIdx.x;
    if (i < N_NODES * H1)    acc1[i] = 0.f;
    if (i < N_NODES * HEADS) { m1[i] = -__builtin_inff(); dn1[i] = 0.f; }
    if (i < N_NODES)         { m2[i] = -__builtin_inff(); dn2[i] = 0.f; }
    if (i < N_NODES * FOUT)  out[i] = 0.f;
}

// ---- layer1 GEMM: xl = x@W1l, xr = x@W1r  (one thread per output) -------
__global__ void k_gemm1(const float* __restrict__ x, const float* __restrict__ Wl,
                        const float* __restrict__ Wr, float* __restrict__ xl,
                        float* __restrict__ xr) {
    int idx = blockIdx.x * blockDim.x + threadIdx.x;
    if (idx >= N_NODES * 2 * H1) return;
    int n = idx / (2 * H1);
    int c = idx % (2 * H1);
    const float* W; int cc;
    if (c < H1) { W = Wl; cc = c; } else { W = Wr; cc = c - H1; }
    const float4* xrow = (const float4*)(x + n * F_IN);
    float acc = 0.f;
#pragma unroll
    for (int k4 = 0; k4 < F_IN / 4; ++k4) {
        float4 xv = xrow[k4];
        int k = k4 * 4;
        acc += xv.x * W[(k + 0) * H1 + cc];
        acc += xv.y * W[(k + 1) * H1 + cc];
        acc += xv.z * W[(k + 2) * H1 + cc];
        acc += xv.w * W[(k + 3) * H1 + cc];
    }
    if (c < H1) xl[n * H1 + cc] = acc; else xr[n * H1 + cc] = acc;
}

// ---- layer1 edge pass A: logits + segment max ---------------------------
__global__ void k_edge1_logits(const int* __restrict__ ei, const float* __restrict__ xl,
                               const float* __restrict__ xr, const float* __restrict__ att,
                               float* __restrict__ lg1, float* __restrict__ m1) {
    int idx = blockIdx.x * blockDim.x + threadIdx.x;
    if (idx >= E_TOT * HEADS) return;
    int e = idx / HEADS, h = idx % HEADS;
    int s, d;
    if (e < E_IN) { s = ei[e]; d = ei[E_IN + e]; } else { s = d = e - E_IN; }
    const float4* a = (const float4*)(xl + s * H1 + h * DH);
    const float4* b = (const float4*)(xr + d * H1 + h * DH);
    const float4* t = (const float4*)(att + h * DH);
    float4 a0 = a[0], a1 = a[1], b0 = b[0], b1 = b[1], t0 = t[0], t1 = t[1];
    float lg = 0.f;
    lg += t0.x * lrelu(a0.x + b0.x);
    lg += t0.y * lrelu(a0.y + b0.y);
    lg += t0.z * lrelu(a0.z + b0.z);
    lg += t0.w * lrelu(a0.w + b0.w);
    lg += t1.x * lrelu(a1.x + b1.x);
    lg += t1.y * lrelu(a1.y + b1.y);
    lg += t1.z * lrelu(a1.z + b1.z);
    lg += t1.w * lrelu(a1.w + b1.w);
    lg1[idx] = lg;
    atomicMaxF(&m1[d * HEADS + h], lg);
}

// ---- layer1 edge pass B: ex = exp(lg-m); denom += ex; acc += ex*xl[src] --
__global__ void k_edge1_accum(const int* __restrict__ ei, const float* __restrict__ xl,
                              const float* __restrict__ lg1, const float* __restrict__ m1,
                              float* __restrict__ dn1, float* __restrict__ acc1) {
    int idx = blockIdx.x * blockDim.x + threadIdx.x;
    if (idx >= E_TOT * HEADS) return;
    int e = idx / HEADS, h = idx % HEADS;
    int s, d;
    if (e < E_IN) { s = ei[e]; d = ei[E_IN + e]; } else { s = d = e - E_IN; }
    float ex = __expf(lg1[idx] - m1[d * HEADS + h]);
    atomicAdd(&dn1[d * HEADS + h], ex);
    const float4* a = (const float4*)(xl + s * H1 + h * DH);
    float4 a0 = a[0], a1 = a[1];
    float* o = acc1 + d * H1 + h * DH;
    atomicAdd(o + 0, ex * a0.x);
    atomicAdd(o + 1, ex * a0.y);
    atomicAdd(o + 2, ex * a0.z);
    atomicAdd(o + 3, ex * a0.w);
    atomicAdd(o + 4, ex * a1.x);
    atomicAdd(o + 5, ex * a1.y);
    atomicAdd(o + 6, ex * a1.z);
    atomicAdd(o + 7, ex * a1.w);
}

// ---- layer1 finish: h1 = relu(acc/denom + b1) ---------------------------
__global__ void k_finish1(const float* __restrict__ acc1, const float* __restrict__ dn1,
                          const float* __restrict__ b1, float* __restrict__ h1) {
    int i = blockIdx.x * blockDim.x + threadIdx.x;
    if (i >= N_NODES * H1) return;
    int n = i / H1, c = i % H1;
    float v = acc1[i] / dn1[n * HEADS + c / DH] + b1[c];
    h1[i] = fmaxf(v, 0.f);
}

// ---- layer2 GEMM: yl = h1@W2l, yr = h1@W2r ------------------------------
__global__ void k_gemm2(const float* __restrict__ h1, const float* __restrict__ Wl,
                        const float* __restrict__ Wr, float* __restrict__ yl,
                        float* __restrict__ yr) {
    int idx = blockIdx.x * blockDim.x + threadIdx.x;
    if (idx >= N_NODES * 2 * FOUT) return;
    int n = idx / (2 * FOUT);
    int c = idx % (2 * FOUT);
    const float* W; int cc;
    if (c < FOUT) { W = Wl; cc = c; } else { W = Wr; cc = c - FOUT; }
    const float4* hrow = (const float4*)(h1 + n * H1);
    float acc = 0.f;
#pragma unroll
    for (int k4 = 0; k4 < H1 / 4; ++k4) {
        float4 hv = hrow[k4];
        int k = k4 * 4;
        acc += hv.x * W[(k + 0) * FOUT + cc];
        acc += hv.y * W[(k + 1) * FOUT + cc];
        acc += hv.z * W[(k + 2) * FOUT + cc];
        acc += hv.w * W[(k + 3) * FOUT + cc];
    }
    if (c < FOUT) yl[n * FOUT + cc] = acc; else yr[n * FOUT + cc] = acc;
}

// ---- layer2 edge pass A -------------------------------------------------
__global__ void k_edge2_logits(const int* __restrict__ ei, const float* __restrict__ yl,
                               const float* __restrict__ yr, const float* __restrict__ att,
                               float* __restrict__ lg2, float* __restrict__ m2) {
    int e = blockIdx.x * blockDim.x + threadIdx.x;
    if (e >= E_TOT) return;
    int s, d;
    if (e < E_IN) { s = ei[e]; d = ei[E_IN + e]; } else { s = d = e - E_IN; }
    const float4* a = (const float4*)(yl + s * FOUT);
    const float4* b = (const float4*)(yr + d * FOUT);
    const float4* t = (const float4*)att;
    float lg = 0.f;
#pragma unroll
    for (int j = 0; j < 4; ++j) {
        float4 av = a[j], bv = b[j], tv = t[j];
        lg += tv.x * lrelu(av.x + bv.x);
        lg += tv.y * lrelu(av.y + bv.y);
        lg += tv.z * lrelu(av.z + bv.z);
        lg += tv.w * lrelu(av.w + bv.w);
    }
    lg2[e] = lg;
    atomicMaxF(&m2[d], lg);
}

// ---- layer2 edge pass B -------------------------------------------------
__global__ void k_edge2_accum(const int* __restrict__ ei, const float* __restrict__ yl,
                              const float* __restrict__ lg2, const float* __restrict__ m2,
                              float* __restrict__ dn2, float* __restrict__ acc2) {
    int e = blockIdx.x * blockDim.x + threadIdx.x;
    if (e >= E_TOT) return;
    int s, d;
    if (e < E_IN) { s = ei[e]; d = ei[E_IN + e]; } else { s = d = e - E_IN; }
    float ex = __expf(lg2[e] - m2[d]);
    atomicAdd(&dn2[d], ex);
    const float4* a = (const float4*)(yl + s * FOUT);
    float* o = acc2 + d * FOUT;
#pragma unroll
    for (int j = 0; j < 4; ++j) {
        float4 av = a[j];
        atomicAdd(o + j * 4 + 0, ex * av.x);
        atomicAdd(o + j * 4 + 1, ex * av.y);
        atomicAdd(o + j * 4 + 2, ex * av.z);
        atomicAdd(o + j * 4 + 3, ex * av.w);
    }
}

// ---- layer2 finish: out = out/denom + b2 (in place) ---------------------
__global__ void k_finish2(float* __restrict__ out, const float* __restrict__ dn2,
                          const float* __restrict__ b2) {
    int i = blockIdx.x * blockDim.x + threadIdx.x;
    if (i >= N_NODES * FOUT) return;
    int n = i / FOUT, c = i % FOUT;
    out[i] = out[i] / dn2[n] + b2[c];
}

extern "C" void kernel_launch(void* const* d_in, const int* in_sizes, int n_in,
                              void* d_out, int out_size, void* d_ws, size_t ws_size,
                              hipStream_t stream) {
    const float* x    = (const float*)d_in[0];
    const int*   ei   = (const int*)d_in[1];
    const float* W1l  = (const float*)d_in[2];
    const float* W1r  = (const float*)d_in[3];
    const float* att1 = (const float*)d_in[4];
    const float* b1   = (const float*)d_in[5];
    const float* W2l  = (const float*)d_in[6];
    const float* W2r  = (const float*)d_in[7];
    const float* att2 = (const float*)d_in[8];
    const float* b2   = (const float*)d_in[9];

    float* ws   = (float*)d_ws;
    float* xl1  = ws;              // 4,000,000
    float* xr1  = ws +  4000000;   // 4,000,000 (reused as h1)
    float* lg1  = ws +  8000000;   // 8,500,000 (reused as yl/yr)
    float* m1   = ws + 16500000;   //   500,000
    float* dn1  = ws + 17000000;   //   500,000
    float* acc1 = ws + 17500000;   // 4,000,000
    float* lg2  = ws + 21500000;   //   850,000
    float* m2   = ws + 22350000;   //    50,000
    float* dn2  = ws + 22400000;   //    50,000
    float* h1   = xr1;             // alias: xr1 dead after edge1 logits
    float* yl   = lg1;             // alias: lg1 dead after edge1 accum
    float* yr   = lg1 + 800000;
    float* acc2 = (float*)d_out;   // accumulate layer2 directly into output

    const int B = 256;
    k_init<<<(4000000 + B - 1) / B, B, 0, stream>>>(m1, dn1, acc1, m2, dn2, acc2);
    k_gemm1<<<(N_NODES * 2 * H1 + B - 1) / B, B, 0, stream>>>(x, W1l, W1r, xl1, xr1);
    k_edge1_logits<<<(E_TOT * HEADS + B - 1) / B, B, 0, stream>>>(ei, xl1, xr1, att1, lg1, m1);
    k_edge1_accum<<<(E_TOT * HEADS + B - 1) / B, B, 0, stream>>>(ei, xl1, lg1, m1, dn1, acc1);
    k_finish1<<<(N_NODES * H1 + B - 1) / B, B, 0, stream>>>(acc1, dn1, b1, h1);
    k_gemm2<<<(N_NODES * 2 * FOUT + B - 1) / B, B, 0, stream>>>(h1, W2l, W2r, yl, yr);
    k_edge2_logits<<<(E_TOT + B - 1) / B, B, 0, stream>>>(ei, yl, yr, att2, lg2, m2);
    k_edge2_accum<<<(E_TOT + B - 1) / B, B, 0, stream>>>(ei, yl, lg2, m2, dn2, acc2);
    k_finish2<<<(N_NODES * FOUT + B - 1) / B, B, 0, stream>>>(acc2, dn2, b2);
}

// Round 4
// 509.034 us; speedup vs baseline: 6.2162x; 6.2162x over previous
//
#include <hip/hip_runtime.h>

#define N_NODES 50000
#define F_IN    128
#define HEADS   10
#define DH      8
#define H1      80      // HEADS*DH
#define FOUT    16
#define E_IN    800000
#define E_TOT   850000  // + N self loops
#define SCAN_T  1024
#define CHUNK   ((N_NODES + SCAN_T - 1) / SCAN_T)   // 49

__device__ __forceinline__ float lrelu(float v) { return v > 0.f ? v : 0.2f * v; }

// ---- CSR build: zero counts --------------------------------------------
__global__ void k_zero(int* __restrict__ cnt) {
    int i = blockIdx.x * blockDim.x + threadIdx.x;
    if (i < N_NODES) cnt[i] = 0;
}

// ---- CSR build: in-degree histogram (self-loops included) ---------------
__global__ void k_count(const int* __restrict__ ei, int* __restrict__ cnt) {
    int e = blockIdx.x * blockDim.x + threadIdx.x;
    if (e >= E_TOT) return;
    int d = (e < E_IN) ? ei[E_IN + e] : e - E_IN;
    atomicAdd(&cnt[d], 1);
}

// ---- CSR build: single-block scan -> row_ptr + scatter cursors ----------
__global__ void __launch_bounds__(SCAN_T) k_scan(const int* __restrict__ cnt,
                                                 int* __restrict__ row_ptr,
                                                 int* __restrict__ cursor) {
    __shared__ int sh[SCAN_T];
    int t = threadIdx.x;
    int base = t * CHUNK;
    int end = min(base + CHUNK, N_NODES);
    int sum = 0;
    for (int i = base; i < end; ++i) sum += cnt[i];
    sh[t] = sum;
    __syncthreads();
    for (int off = 1; off < SCAN_T; off <<= 1) {
        int v = (t >= off) ? sh[t - off] : 0;
        __syncthreads();
        sh[t] += v;
        __syncthreads();
    }
    int run = (t > 0) ? sh[t - 1] : 0;
    for (int i = base; i < end; ++i) {
        row_ptr[i] = run;
        cursor[i]  = run;
        run += cnt[i];
    }
    if (t == SCAN_T - 1) row_ptr[N_NODES] = E_TOT;
}

// ---- CSR build: scatter src ids bucketed by dst -------------------------
__global__ void k_fill(const int* __restrict__ ei, int* __restrict__ cursor,
                       int* __restrict__ csr_src) {
    int e = blockIdx.x * blockDim.x + threadIdx.x;
    if (e >= E_TOT) return;
    int s, d;
    if (e < E_IN) { s = ei[e]; d = ei[E_IN + e]; } else { s = d = e - E_IN; }
    int pos = atomicAdd(&cursor[d], 1);
    csr_src[pos] = s;
}

// ---- layer1 GEMM: xl = x@W1l, xr = x@W1r (4 outputs / thread) -----------
__global__ void k_gemm1(const float* __restrict__ x, const float* __restrict__ Wl,
                        const float* __restrict__ Wr, float* __restrict__ xl,
                        float* __restrict__ xr) {
    int idx = blockIdx.x * blockDim.x + threadIdx.x;
    if (idx >= N_NODES * 40) return;
    int n = idx / 40, g = idx % 40;
    const float* W; float* o; int cc;
    if (g < 20) { W = Wl; o = xl; cc = g * 4; }
    else        { W = Wr; o = xr; cc = (g - 20) * 4; }
    const float4* xrow = (const float4*)(x + (size_t)n * F_IN);
    float4 acc = {0.f, 0.f, 0.f, 0.f};
#pragma unroll 8
    for (int k4 = 0; k4 < F_IN / 4; ++k4) {
        float4 xv = xrow[k4];
        int k = k4 * 4;
        float4 w0 = *(const float4*)(W + (size_t)(k + 0) * H1 + cc);
        float4 w1 = *(const float4*)(W + (size_t)(k + 1) * H1 + cc);
        float4 w2 = *(const float4*)(W + (size_t)(k + 2) * H1 + cc);
        float4 w3 = *(const float4*)(W + (size_t)(k + 3) * H1 + cc);
        acc.x += xv.x * w0.x + xv.y * w1.x + xv.z * w2.x + xv.w * w3.x;
        acc.y += xv.x * w0.y + xv.y * w1.y + xv.z * w2.y + xv.w * w3.y;
        acc.z += xv.x * w0.z + xv.y * w1.z + xv.z * w2.z + xv.w * w3.z;
        acc.w += xv.x * w0.w + xv.y * w1.w + xv.z * w2.w + xv.w * w3.w;
    }
    *(float4*)(o + (size_t)n * H1 + cc) = acc;
}

// ---- layer1 aggregate: per (node,head) online softmax over CSR edges ----
// fuses: logits + segment max + exp + denom + weighted sum + bias + relu
__global__ void k_agg1(const int* __restrict__ row_ptr, const int* __restrict__ csr_src,
                       const float* __restrict__ xl, const float* __restrict__ xr,
                       const float* __restrict__ att, const float* __restrict__ b1,
                       float* __restrict__ h1) {
    int idx = blockIdx.x * blockDim.x + threadIdx.x;
    if (idx >= N_NODES * HEADS) return;
    int n = idx / HEADS, h = idx % HEADS;
    const float4* xrp = (const float4*)(xr + (size_t)n * H1 + h * DH);
    float4 r0 = xrp[0], r1 = xrp[1];
    const float4* atp = (const float4*)(att + h * DH);
    float4 t0 = atp[0], t1 = atp[1];
    float m = -__builtin_inff(), den = 0.f;
    float4 ac0 = {0.f,0.f,0.f,0.f}, ac1 = {0.f,0.f,0.f,0.f};
    int p0 = row_ptr[n], p1 = row_ptr[n + 1];
    for (int p = p0; p < p1; ++p) {
        int s = csr_src[p];
        const float4* ap = (const float4*)(xl + (size_t)s * H1 + h * DH);
        float4 a0 = ap[0], a1 = ap[1];
        float lg = t0.x * lrelu(a0.x + r0.x) + t0.y * lrelu(a0.y + r0.y)
                 + t0.z * lrelu(a0.z + r0.z) + t0.w * lrelu(a0.w + r0.w)
                 + t1.x * lrelu(a1.x + r1.x) + t1.y * lrelu(a1.y + r1.y)
                 + t1.z * lrelu(a1.z + r1.z) + t1.w * lrelu(a1.w + r1.w);
        float nm = fmaxf(m, lg);
        float sc = __expf(m - nm);   // 0 on first iter (m = -inf)
        float ex = __expf(lg - nm);
        m = nm;
        den = den * sc + ex;
        ac0.x = ac0.x * sc + ex * a0.x;
        ac0.y = ac0.y * sc + ex * a0.y;
        ac0.z = ac0.z * sc + ex * a0.z;
        ac0.w = ac0.w * sc + ex * a0.w;
        ac1.x = ac1.x * sc + ex * a1.x;
        ac1.y = ac1.y * sc + ex * a1.y;
        ac1.z = ac1.z * sc + ex * a1.z;
        ac1.w = ac1.w * sc + ex * a1.w;
    }
    float inv = 1.f / den;
    const float4* bp = (const float4*)(b1 + h * DH);
    float4 b0 = bp[0], b1v = bp[1];
    float4 o0, o1;
    o0.x = fmaxf(ac0.x * inv + b0.x, 0.f);
    o0.y = fmaxf(ac0.y * inv + b0.y, 0.f);
    o0.z = fmaxf(ac0.z * inv + b0.z, 0.f);
    o0.w = fmaxf(ac0.w * inv + b0.w, 0.f);
    o1.x = fmaxf(ac1.x * inv + b1v.x, 0.f);
    o1.y = fmaxf(ac1.y * inv + b1v.y, 0.f);
    o1.z = fmaxf(ac1.z * inv + b1v.z, 0.f);
    o1.w = fmaxf(ac1.w * inv + b1v.w, 0.f);
    float4* op = (float4*)(h1 + (size_t)n * H1 + h * DH);
    op[0] = o0; op[1] = o1;
}

// ---- layer2 GEMM: yl = h1@W2l, yr = h1@W2r (4 outputs / thread) ---------
__global__ void k_gemm2(const float* __restrict__ h1, const float* __restrict__ Wl,
                        const float* __restrict__ Wr, float* __restrict__ yl,
                        float* __restrict__ yr) {
    int idx = blockIdx.x * blockDim.x + threadIdx.x;
    if (idx >= N_NODES * 8) return;
    int n = idx / 8, g = idx % 8;
    const float* W; float* o; int cc;
    if (g < 4) { W = Wl; o = yl; cc = g * 4; }
    else       { W = Wr; o = yr; cc = (g - 4) * 4; }
    const float4* hrow = (const float4*)(h1 + (size_t)n * H1);
    float4 acc = {0.f, 0.f, 0.f, 0.f};
#pragma unroll 5
    for (int k4 = 0; k4 < H1 / 4; ++k4) {
        float4 hv = hrow[k4];
        int k = k4 * 4;
        float4 w0 = *(const float4*)(W + (size_t)(k + 0) * FOUT + cc);
        float4 w1 = *(const float4*)(W + (size_t)(k + 1) * FOUT + cc);
        float4 w2 = *(const float4*)(W + (size_t)(k + 2) * FOUT + cc);
        float4 w3 = *(const float4*)(W + (size_t)(k + 3) * FOUT + cc);
        acc.x += hv.x * w0.x + hv.y * w1.x + hv.z * w2.x + hv.w * w3.x;
        acc.y += hv.x * w0.y + hv.y * w1.y + hv.z * w2.y + hv.w * w3.y;
        acc.z += hv.x * w0.z + hv.y * w1.z + hv.z * w2.z + hv.w * w3.z;
        acc.w += hv.x * w0.w + hv.y * w1.w + hv.z * w2.w + hv.w * w3.w;
    }
    *(float4*)(o + (size_t)n * FOUT + cc) = acc;
}

// ---- layer2 aggregate: lane-quad per node, online softmax ---------------
__global__ void k_agg2(const int* __restrict__ row_ptr, const int* __restrict__ csr_src,
                       const float* __restrict__ yl, const float* __restrict__ yr,
                       const float* __restrict__ att, const float* __restrict__ b2,
                       float* __restrict__ out) {
    int idx = blockIdx.x * blockDim.x + threadIdx.x;
    if (idx >= N_NODES * 4) return;
    int n = idx >> 2, q = idx & 3;
    float4 r = ((const float4*)(yr + (size_t)n * FOUT))[q];
    float4 t = ((const float4*)att)[q];
    float m = -__builtin_inff(), den = 0.f;
    float4 acc = {0.f, 0.f, 0.f, 0.f};
    int p0 = row_ptr[n], p1 = row_ptr[n + 1];
    for (int p = p0; p < p1; ++p) {
        int s = csr_src[p];
        float4 a = ((const float4*)(yl + (size_t)s * FOUT))[q];
        float part = t.x * lrelu(a.x + r.x) + t.y * lrelu(a.y + r.y)
                   + t.z * lrelu(a.z + r.z) + t.w * lrelu(a.w + r.w);
        part += __shfl_xor(part, 1);
        part += __shfl_xor(part, 2);   // full 16-dim logit in all 4 lanes
        float nm = fmaxf(m, part);
        float sc = __expf(m - nm);
        float ex = __expf(part - nm);
        m = nm;
        den = den * sc + ex;
        acc.x = acc.x * sc + ex * a.x;
        acc.y = acc.y * sc + ex * a.y;
        acc.z = acc.z * sc + ex * a.z;
        acc.w = acc.w * sc + ex * a.w;
    }
    float inv = 1.f / den;
    float4 bb = ((const float4*)b2)[q];
    float4 o = {acc.x * inv + bb.x, acc.y * inv + bb.y,
                acc.z * inv + bb.z, acc.w * inv + bb.w};
    ((float4*)(out + (size_t)n * FOUT))[q] = o;
}

extern "C" void kernel_launch(void* const* d_in, const int* in_sizes, int n_in,
                              void* d_out, int out_size, void* d_ws, size_t ws_size,
                              hipStream_t stream) {
    const float* x    = (const float*)d_in[0];
    const int*   ei   = (const int*)d_in[1];
    const float* W1l  = (const float*)d_in[2];
    const float* W1r  = (const float*)d_in[3];
    const float* att1 = (const float*)d_in[4];
    const float* b1   = (const float*)d_in[5];
    const float* W2l  = (const float*)d_in[6];
    const float* W2r  = (const float*)d_in[7];
    const float* att2 = (const float*)d_in[8];
    const float* b2   = (const float*)d_in[9];

    float* ws = (float*)d_ws;
    float* xl = ws;                 // 4,000,000 f
    float* xr = ws +  4000000;      // 4,000,000 f
    float* h1 = ws +  8000000;      // 4,000,000 f
    float* yl = ws + 12000000;      //   800,000 f
    float* yr = ws + 12800000;      //   800,000 f
    int* cnt     = (int*)(ws + 13600000);  //    50,000 i
    int* row_ptr = cnt + 50000;            //    50,001 i
    int* cursor  = row_ptr + 50001;        //    50,000 i
    int* csr_src = cursor + 50000;         //   850,000 i
    float* out = (float*)d_out;

    const int B = 256;
    // CSR build (counting sort by dst)
    k_zero <<<(N_NODES + B - 1) / B, B, 0, stream>>>(cnt);
    k_count<<<(E_TOT + B - 1) / B, B, 0, stream>>>(ei, cnt);
    k_scan <<<1, SCAN_T, 0, stream>>>(cnt, row_ptr, cursor);
    k_fill <<<(E_TOT + B - 1) / B, B, 0, stream>>>(ei, cursor, csr_src);
    // layer 1
    k_gemm1<<<(N_NODES * 40 + B - 1) / B, B, 0, stream>>>(x, W1l, W1r, xl, xr);
    k_agg1 <<<(N_NODES * HEADS + B - 1) / B, B, 0, stream>>>(row_ptr, csr_src, xl, xr, att1, b1, h1);
    // layer 2
    k_gemm2<<<(N_NODES * 8 + B - 1) / B, B, 0, stream>>>(h1, W2l, W2r, yl, yr);
    k_agg2 <<<(N_NODES * 4 + B - 1) / B, B, 0, stream>>>(row_ptr, csr_src, yl, yr, att2, b2, out);
}

// Round 7
// 456.592 us; speedup vs baseline: 6.9301x; 1.1149x over previous
//
#include <hip/hip_runtime.h>

#define N_NODES 50000
#define F_IN    128
#define HEADS   10
#define DH      8
#define H1      80      // HEADS*DH
#define FOUT    16
#define E_IN    800000
#define E_TOT   850000  // + N self loops
#define SCAN_T  1024
#define CHUNK   ((N_NODES + SCAN_T - 1) / SCAN_T)   // 49

// gemm1 tiling
#define GN  32           // nodes per block
#define KC  32           // k-chunk staged in LDS
#define BPAD 164         // Bs row stride (words), 16B-aligned

__device__ __forceinline__ float lrelu(float v) { return v > 0.f ? v : 0.2f * v; }

// ---- CSR build: zero counts --------------------------------------------
__global__ void k_zero(int* __restrict__ cnt) {
    int i = blockIdx.x * blockDim.x + threadIdx.x;
    if (i < N_NODES) cnt[i] = 0;
}

// ---- CSR build: in-degree histogram (self-loops included) ---------------
__global__ void k_count(const int* __restrict__ ei, int* __restrict__ cnt) {
    int e = blockIdx.x * blockDim.x + threadIdx.x;
    if (e >= E_TOT) return;
    int d = (e < E_IN) ? ei[E_IN + e] : e - E_IN;
    atomicAdd(&cnt[d], 1);
}

// ---- CSR build: single-block scan -> row_ptr + scatter cursors ----------
__global__ void __launch_bounds__(SCAN_T) k_scan(const int* __restrict__ cnt,
                                                 int* __restrict__ row_ptr,
                                                 int* __restrict__ cursor) {
    __shared__ int sh[SCAN_T];
    int t = threadIdx.x;
    int base = t * CHUNK;
    int end = min(base + CHUNK, N_NODES);
    int sum = 0;
    for (int i = base; i < end; ++i) sum += cnt[i];
    sh[t] = sum;
    __syncthreads();
    for (int off = 1; off < SCAN_T; off <<= 1) {
        int v = (t >= off) ? sh[t - off] : 0;
        __syncthreads();
        sh[t] += v;
        __syncthreads();
    }
    int run = (t > 0) ? sh[t - 1] : 0;
    for (int i = base; i < end; ++i) {
        row_ptr[i] = run;
        cursor[i]  = run;
        run += cnt[i];
    }
    if (t == SCAN_T - 1) row_ptr[N_NODES] = E_TOT;
}

// ---- CSR build: scatter src ids bucketed by dst -------------------------
__global__ void k_fill(const int* __restrict__ ei, int* __restrict__ cursor,
                       int* __restrict__ csr_src) {
    int e = blockIdx.x * blockDim.x + threadIdx.x;
    if (e >= E_TOT) return;
    int s, d;
    if (e < E_IN) { s = ei[e]; d = ei[E_IN + e]; } else { s = d = e - E_IN; }
    int pos = atomicAdd(&cursor[d], 1);
    csr_src[pos] = s;
}

// ---- layer1 GEMM, LDS-tiled: [xl|xr] = x @ [W1l|W1r] --------------------
// block 320 = 8 node-groups(4 nodes) x 40 col-groups(4 cols); W k-chunk in LDS
__global__ void __launch_bounds__(320) k_gemm1t(const float* __restrict__ x,
                                                const float* __restrict__ Wl,
                                                const float* __restrict__ Wr,
                                                float* __restrict__ xl,
                                                float* __restrict__ xr) {
    __shared__ float Bs[KC][BPAD];
    int t  = threadIdx.x;
    int cg = t % 40;          // col group: 4 cols of the fused 160
    int ng = t / 40;          // node group: 4 nodes
    int n0 = blockIdx.x * GN;
    int cg4 = cg * 4;

    // x row pointers (clamped for tail block; stores are guarded)
    int nd[4];
    const float* xp[4];
#pragma unroll
    for (int i = 0; i < 4; ++i) {
        nd[i] = n0 + ng * 4 + i;
        int nc = nd[i] < N_NODES ? nd[i] : N_NODES - 1;
        xp[i] = x + (size_t)nc * F_IN;
    }

    float4 acc0 = {0,0,0,0}, acc1 = {0,0,0,0}, acc2 = {0,0,0,0}, acc3 = {0,0,0,0};

    for (int kc = 0; kc < F_IN / KC; ++kc) {
        int k0 = kc * KC;
        // stage fused W chunk: Bs[kk][c] = c<80 ? Wl[k0+kk][c] : Wr[k0+kk][c-80]
#pragma unroll
        for (int it = 0; it < 4; ++it) {
            int i = t + it * 320;            // 1280 float4 items
            int kk = i / 40, c4 = i % 40;
            const float* src = (c4 < 20) ? (Wl + (size_t)(k0 + kk) * H1 + c4 * 4)
                                         : (Wr + (size_t)(k0 + kk) * H1 + (c4 - 20) * 4);
            *(float4*)&Bs[kk][c4 * 4] = *(const float4*)src;
        }
        __syncthreads();
#pragma unroll
        for (int k4 = 0; k4 < KC / 4; ++k4) {
            int kk = k4 * 4;
            float4 a0 = *(const float4*)(xp[0] + k0 + kk);
            float4 a1 = *(const float4*)(xp[1] + k0 + kk);
            float4 a2 = *(const float4*)(xp[2] + k0 + kk);
            float4 a3 = *(const float4*)(xp[3] + k0 + kk);
            float4 b0 = *(const float4*)&Bs[kk + 0][cg4];
            float4 b1 = *(const float4*)&Bs[kk + 1][cg4];
            float4 b2 = *(const float4*)&Bs[kk + 2][cg4];
            float4 b3 = *(const float4*)&Bs[kk + 3][cg4];
            acc0.x += a0.x*b0.x + a0.y*b1.x + a0.z*b2.x + a0.w*b3.x;
            acc0.y += a0.x*b0.y + a0.y*b1.y + a0.z*b2.y + a0.w*b3.y;
            acc0.z += a0.x*b0.z + a0.y*b1.z + a0.z*b2.z + a0.w*b3.z;
            acc0.w += a0.x*b0.w + a0.y*b1.w + a0.z*b2.w + a0.w*b3.w;
            acc1.x += a1.x*b0.x + a1.y*b1.x + a1.z*b2.x + a1.w*b3.x;
            acc1.y += a1.x*b0.y + a1.y*b1.y + a1.z*b2.y + a1.w*b3.y;
            acc1.z += a1.x*b0.z + a1.y*b1.z + a1.z*b2.z + a1.w*b3.z;
            acc1.w += a1.x*b0.w + a1.y*b1.w + a1.z*b2.w + a1.w*b3.w;
            acc2.x += a2.x*b0.x + a2.y*b1.x + a2.z*b2.x + a2.w*b3.x;
            acc2.y += a2.x*b0.y + a2.y*b1.y + a2.z*b2.y + a2.w*b3.y;
            acc2.z += a2.x*b0.z + a2.y*b1.z + a2.z*b2.z + a2.w*b3.z;
            acc2.w += a2.x*b0.w + a2.y*b1.w + a2.z*b2.w + a2.w*b3.w;
            acc3.x += a3.x*b0.x + a3.y*b1.x + a3.z*b2.x + a3.w*b3.x;
            acc3.y += a3.x*b0.y + a3.y*b1.y + a3.z*b2.y + a3.w*b3.y;
            acc3.z += a3.x*b0.z + a3.y*b1.z + a3.z*b2.z + a3.w*b3.z;
            acc3.w += a3.x*b0.w + a3.y*b1.w + a3.z*b2.w + a3.w*b3.w;
        }
        __syncthreads();
    }
    // store: cg<20 -> xl col cg4 ; else xr col cg4-80
    float* obase; int oc;
    if (cg < 20) { obase = xl; oc = cg4; } else { obase = xr; oc = cg4 - 80; }
    if (nd[0] < N_NODES) *(float4*)(obase + (size_t)nd[0] * H1 + oc) = acc0;
    if (nd[1] < N_NODES) *(float4*)(obase + (size_t)nd[1] * H1 + oc) = acc1;
    if (nd[2] < N_NODES) *(float4*)(obase + (size_t)nd[2] * H1 + oc) = acc2;
    if (nd[3] < N_NODES) *(float4*)(obase + (size_t)nd[3] * H1 + oc) = acc3;
}

// ---- layer1 aggregate: per (node,head) online softmax over CSR edges ----
__global__ void k_agg1(const int* __restrict__ row_ptr, const int* __restrict__ csr_src,
                       const float* __restrict__ xl, const float* __restrict__ xr,
                       const float* __restrict__ att, const float* __restrict__ b1,
                       float* __restrict__ h1) {
    int idx = blockIdx.x * blockDim.x + threadIdx.x;
    if (idx >= N_NODES * HEADS) return;
    int n = idx / HEADS, h = idx % HEADS;
    const float4* xrp = (const float4*)(xr + (size_t)n * H1 + h * DH);
    float4 r0 = xrp[0], r1 = xrp[1];
    const float4* atp = (const float4*)(att + h * DH);
    float4 t0 = atp[0], t1 = atp[1];
    float m = -__builtin_inff(), den = 0.f;
    float4 ac0 = {0.f,0.f,0.f,0.f}, ac1 = {0.f,0.f,0.f,0.f};
    int p0 = row_ptr[n], p1 = row_ptr[n + 1];
    for (int p = p0; p < p1; ++p) {
        int s = csr_src[p];
        const float4* ap = (const float4*)(xl + (size_t)s * H1 + h * DH);
        float4 a0 = ap[0], a1 = ap[1];
        float lg = t0.x * lrelu(a0.x + r0.x) + t0.y * lrelu(a0.y + r0.y)
                 + t0.z * lrelu(a0.z + r0.z) + t0.w * lrelu(a0.w + r0.w)
                 + t1.x * lrelu(a1.x + r1.x) + t1.y * lrelu(a1.y + r1.y)
                 + t1.z * lrelu(a1.z + r1.z) + t1.w * lrelu(a1.w + r1.w);
        // one-exp online softmax: either the rescale or the new term is exp(0)=1
        float dd = lg - m;                 // first iter: +inf
        bool up = dd > 0.f;
        float e = __expf(up ? -dd : dd);   // exp(-|dd|); first iter -> 0
        float sc = up ? e : 1.f;
        float ex = up ? 1.f : e;
        if (up) m = lg;
        den = den * sc + ex;
        ac0.x = ac0.x * sc + ex * a0.x;
        ac0.y = ac0.y * sc + ex * a0.y;
        ac0.z = ac0.z * sc + ex * a0.z;
        ac0.w = ac0.w * sc + ex * a0.w;
        ac1.x = ac1.x * sc + ex * a1.x;
        ac1.y = ac1.y * sc + ex * a1.y;
        ac1.z = ac1.z * sc + ex * a1.z;
        ac1.w = ac1.w * sc + ex * a1.w;
    }
    float inv = 1.f / den;
    const float4* bp = (const float4*)(b1 + h * DH);
    float4 b0 = bp[0], b1v = bp[1];
    float4 o0, o1;
    o0.x = fmaxf(ac0.x * inv + b0.x, 0.f);
    o0.y = fmaxf(ac0.y * inv + b0.y, 0.f);
    o0.z = fmaxf(ac0.z * inv + b0.z, 0.f);
    o0.w = fmaxf(ac0.w * inv + b0.w, 0.f);
    o1.x = fmaxf(ac1.x * inv + b1v.x, 0.f);
    o1.y = fmaxf(ac1.y * inv + b1v.y, 0.f);
    o1.z = fmaxf(ac1.z * inv + b1v.z, 0.f);
    o1.w = fmaxf(ac1.w * inv + b1v.w, 0.f);
    float4* op = (float4*)(h1 + (size_t)n * H1 + h * DH);
    op[0] = o0; op[1] = o1;
}

// ---- layer2 GEMM: yl = h1@W2l, yr = h1@W2r (4 outputs / thread) ---------
__global__ void k_gemm2(const float* __restrict__ h1, const float* __restrict__ Wl,
                        const float* __restrict__ Wr, float* __restrict__ yl,
                        float* __restrict__ yr) {
    int idx = blockIdx.x * blockDim.x + threadIdx.x;
    if (idx >= N_NODES * 8) return;
    int n = idx / 8, g = idx % 8;
    const float* W; float* o; int cc;
    if (g < 4) { W = Wl; o = yl; cc = g * 4; }
    else       { W = Wr; o = yr; cc = (g - 4) * 4; }
    const float4* hrow = (const float4*)(h1 + (size_t)n * H1);
    float4 acc = {0.f, 0.f, 0.f, 0.f};
#pragma unroll 5
    for (int k4 = 0; k4 < H1 / 4; ++k4) {
        float4 hv = hrow[k4];
        int k = k4 * 4;
        float4 w0 = *(const float4*)(W + (size_t)(k + 0) * FOUT + cc);
        float4 w1 = *(const float4*)(W + (size_t)(k + 1) * FOUT + cc);
        float4 w2 = *(const float4*)(W + (size_t)(k + 2) * FOUT + cc);
        float4 w3 = *(const float4*)(W + (size_t)(k + 3) * FOUT + cc);
        acc.x += hv.x * w0.x + hv.y * w1.x + hv.z * w2.x + hv.w * w3.x;
        acc.y += hv.x * w0.y + hv.y * w1.y + hv.z * w2.y + hv.w * w3.y;
        acc.z += hv.x * w0.z + hv.y * w1.z + hv.z * w2.z + hv.w * w3.z;
        acc.w += hv.x * w0.w + hv.y * w1.w + hv.z * w2.w + hv.w * w3.w;
    }
    *(float4*)(o + (size_t)n * FOUT + cc) = acc;
}

// ---- layer2 aggregate: lane-quad per node, online softmax ---------------
__global__ void k_agg2(const int* __restrict__ row_ptr, const int* __restrict__ csr_src,
                       const float* __restrict__ yl, const float* __restrict__ yr,
                       const float* __restrict__ att, const float* __restrict__ b2,
                       float* __restrict__ out) {
    int idx = blockIdx.x * blockDim.x + threadIdx.x;
    if (idx >= N_NODES * 4) return;
    int n = idx >> 2, q = idx & 3;
    float4 r = ((const float4*)(yr + (size_t)n * FOUT))[q];
    float4 t = ((const float4*)att)[q];
    float m = -__builtin_inff(), den = 0.f;
    float4 acc = {0.f, 0.f, 0.f, 0.f};
    int p0 = row_ptr[n], p1 = row_ptr[n + 1];
    for (int p = p0; p < p1; ++p) {
        int s = csr_src[p];
        float4 a = ((const float4*)(yl + (size_t)s * FOUT))[q];
        float part = t.x * lrelu(a.x + r.x) + t.y * lrelu(a.y + r.y)
                   + t.z * lrelu(a.z + r.z) + t.w * lrelu(a.w + r.w);
        part += __shfl_xor(part, 1);
        part += __shfl_xor(part, 2);   // full 16-dim logit in all 4 lanes
        float dd = part - m;
        bool up = dd > 0.f;
        float e = __expf(up ? -dd : dd);
        float sc = up ? e : 1.f;
        float ex = up ? 1.f : e;
        if (up) m = part;
        den = den * sc + ex;
        acc.x = acc.x * sc + ex * a.x;
        acc.y = acc.y * sc + ex * a.y;
        acc.z = acc.z * sc + ex * a.z;
        acc.w = acc.w * sc + ex * a.w;
    }
    float inv = 1.f / den;
    float4 bb = ((const float4*)b2)[q];
    float4 o = {acc.x * inv + bb.x, acc.y * inv + bb.y,
                acc.z * inv + bb.z, acc.w * inv + bb.w};
    ((float4*)(out + (size_t)n * FOUT))[q] = o;
}

extern "C" void kernel_launch(void* const* d_in, const int* in_sizes, int n_in,
                              void* d_out, int out_size, void* d_ws, size_t ws_size,
                              hipStream_t stream) {
    const float* x    = (const float*)d_in[0];
    const int*   ei   = (const int*)d_in[1];
    const float* W1l  = (const float*)d_in[2];
    const float* W1r  = (const float*)d_in[3];
    const float* att1 = (const float*)d_in[4];
    const float* b1   = (const float*)d_in[5];
    const float* W2l  = (const float*)d_in[6];
    const float* W2r  = (const float*)d_in[7];
    const float* att2 = (const float*)d_in[8];
    const float* b2   = (const float*)d_in[9];

    float* ws = (float*)d_ws;
    float* xl = ws;                 // 4,000,000 f
    float* xr = ws +  4000000;      // 4,000,000 f
    float* h1 = ws +  8000000;      // 4,000,000 f
    float* yl = ws + 12000000;      //   800,000 f
    float* yr = ws + 12800000;      //   800,000 f
    int* cnt     = (int*)(ws + 13600000);  //    50,000 i
    int* row_ptr = cnt + 50000;            //    50,001 i
    int* cursor  = row_ptr + 50001;        //    50,000 i
    int* csr_src = cursor + 50000;         //   850,000 i
    float* out = (float*)d_out;

    const int B = 256;
    // CSR build (counting sort by dst)
    k_zero <<<(N_NODES + B - 1) / B, B, 0, stream>>>(cnt);
    k_count<<<(E_TOT + B - 1) / B, B, 0, stream>>>(ei, cnt);
    k_scan <<<1, SCAN_T, 0, stream>>>(cnt, row_ptr, cursor);
    k_fill <<<(E_TOT + B - 1) / B, B, 0, stream>>>(ei, cursor, csr_src);
    // layer 1
    k_gemm1t<<<(N_NODES + GN - 1) / GN, 320, 0, stream>>>(x, W1l, W1r, xl, xr);
    k_agg1 <<<(N_NODES * HEADS + B - 1) / B, B, 0, stream>>>(row_ptr, csr_src, xl, xr, att1, b1, h1);
    // layer 2
    k_gemm2<<<(N_NODES * 8 + B - 1) / B, B, 0, stream>>>(h1, W2l, W2r, yl, yr);
    k_agg2 <<<(N_NODES * 4 + B - 1) / B, B, 0, stream>>>(row_ptr, csr_src, yl, yr, att2, b2, out);
}

// Round 8
// 354.983 us; speedup vs baseline: 8.9138x; 1.2862x over previous
//
#include <hip/hip_runtime.h>

#define N_NODES 50000
#define F_IN    128
#define HEADS   10
#define DH      8
#define H1      80      // HEADS*DH
#define FOUT    16
#define E_IN    800000
#define E_TOT   850000  // + N self loops

// gemm1 tiling
#define GN  32           // nodes per block
#define KC  32           // k-chunk staged in LDS
#define BPAD 164         // Bs row stride (words), 16B-aligned

__device__ __forceinline__ float lrelu(float v) { return v > 0.f ? v : 0.2f * v; }

// ---- CSR build: zero counts + the global bucket counter -----------------
__global__ void k_zero(int* __restrict__ cnt, int* __restrict__ counter) {
    int i = blockIdx.x * blockDim.x + threadIdx.x;
    if (i < N_NODES) cnt[i] = 0;
    if (i == 0) *counter = 0;
}

// ---- CSR build: in-degree histogram (self-loops included) ---------------
__global__ void k_count(const int* __restrict__ ei, int* __restrict__ cnt) {
    int e = blockIdx.x * blockDim.x + threadIdx.x;
    if (e >= E_TOT) return;
    int d = (e < E_IN) ? ei[E_IN + e] : e - E_IN;
    atomicAdd(&cnt[d], 1);
}

// ---- CSR build: bucket starts via wave-prefix + one atomic per wave -----
// Buckets are disjoint but NOT node-ordered — agg kernels only need
// [start[n], start[n]+cnt[n]), so a global prefix scan is unnecessary.
__global__ void k_start(const int* __restrict__ cnt, int* __restrict__ counter,
                        int* __restrict__ start, int* __restrict__ cursor) {
    int i = blockIdx.x * blockDim.x + threadIdx.x;
    int c = (i < N_NODES) ? cnt[i] : 0;
    int lane = threadIdx.x & 63;
    // inclusive 64-lane prefix sum
    int pre = c;
#pragma unroll
    for (int off = 1; off < 64; off <<= 1) {
        int v = __shfl_up(pre, off);
        if (lane >= off) pre += v;
    }
    int waveTotal = __shfl(pre, 63);
    int excl = pre - c;
    int base = 0;
    if (lane == 63) base = atomicAdd(counter, waveTotal);
    base = __shfl(base, 63);
    if (i < N_NODES) { start[i] = base + excl; cursor[i] = base + excl; }
}

// ---- CSR build: scatter src ids bucketed by dst -------------------------
__global__ void k_fill(const int* __restrict__ ei, int* __restrict__ cursor,
                       int* __restrict__ csr_src) {
    int e = blockIdx.x * blockDim.x + threadIdx.x;
    if (e >= E_TOT) return;
    int s, d;
    if (e < E_IN) { s = ei[e]; d = ei[E_IN + e]; } else { s = d = e - E_IN; }
    int pos = atomicAdd(&cursor[d], 1);
    csr_src[pos] = s;
}

// ---- layer1 GEMM, LDS-tiled: [xl|xr] = x @ [W1l|W1r] --------------------
// block 320 = 8 node-groups(4 nodes) x 40 col-groups(4 cols); W k-chunk in LDS
__global__ void __launch_bounds__(320) k_gemm1t(const float* __restrict__ x,
                                                const float* __restrict__ Wl,
                                                const float* __restrict__ Wr,
                                                float* __restrict__ xl,
                                                float* __restrict__ xr) {
    __shared__ float Bs[KC][BPAD];
    int t  = threadIdx.x;
    int cg = t % 40;          // col group: 4 cols of the fused 160
    int ng = t / 40;          // node group: 4 nodes
    int n0 = blockIdx.x * GN;
    int cg4 = cg * 4;

    // x row pointers (clamped for tail block; stores are guarded)
    int nd[4];
    const float* xp[4];
#pragma unroll
    for (int i = 0; i < 4; ++i) {
        nd[i] = n0 + ng * 4 + i;
        int nc = nd[i] < N_NODES ? nd[i] : N_NODES - 1;
        xp[i] = x + (size_t)nc * F_IN;
    }

    float4 acc0 = {0,0,0,0}, acc1 = {0,0,0,0}, acc2 = {0,0,0,0}, acc3 = {0,0,0,0};

    for (int kc = 0; kc < F_IN / KC; ++kc) {
        int k0 = kc * KC;
        // stage fused W chunk: Bs[kk][c] = c<80 ? Wl[k0+kk][c] : Wr[k0+kk][c-80]
#pragma unroll
        for (int it = 0; it < 4; ++it) {
            int i = t + it * 320;            // 1280 float4 items
            int kk = i / 40, c4 = i % 40;
            const float* src = (c4 < 20) ? (Wl + (size_t)(k0 + kk) * H1 + c4 * 4)
                                         : (Wr + (size_t)(k0 + kk) * H1 + (c4 - 20) * 4);
            *(float4*)&Bs[kk][c4 * 4] = *(const float4*)src;
        }
        __syncthreads();
#pragma unroll
        for (int k4 = 0; k4 < KC / 4; ++k4) {
            int kk = k4 * 4;
            float4 a0 = *(const float4*)(xp[0] + k0 + kk);
            float4 a1 = *(const float4*)(xp[1] + k0 + kk);
            float4 a2 = *(const float4*)(xp[2] + k0 + kk);
            float4 a3 = *(const float4*)(xp[3] + k0 + kk);
            float4 b0 = *(const float4*)&Bs[kk + 0][cg4];
            float4 b1 = *(const float4*)&Bs[kk + 1][cg4];
            float4 b2 = *(const float4*)&Bs[kk + 2][cg4];
            float4 b3 = *(const float4*)&Bs[kk + 3][cg4];
            acc0.x += a0.x*b0.x + a0.y*b1.x + a0.z*b2.x + a0.w*b3.x;
            acc0.y += a0.x*b0.y + a0.y*b1.y + a0.z*b2.y + a0.w*b3.y;
            acc0.z += a0.x*b0.z + a0.y*b1.z + a0.z*b2.z + a0.w*b3.z;
            acc0.w += a0.x*b0.w + a0.y*b1.w + a0.z*b2.w + a0.w*b3.w;
            acc1.x += a1.x*b0.x + a1.y*b1.x + a1.z*b2.x + a1.w*b3.x;
            acc1.y += a1.x*b0.y + a1.y*b1.y + a1.z*b2.y + a1.w*b3.y;
            acc1.z += a1.x*b0.z + a1.y*b1.z + a1.z*b2.z + a1.w*b3.z;
            acc1.w += a1.x*b0.w + a1.y*b1.w + a1.z*b2.w + a1.w*b3.w;
            acc2.x += a2.x*b0.x + a2.y*b1.x + a2.z*b2.x + a2.w*b3.x;
            acc2.y += a2.x*b0.y + a2.y*b1.y + a2.z*b2.y + a2.w*b3.y;
            acc2.z += a2.x*b0.z + a2.y*b1.z + a2.z*b2.z + a2.w*b3.z;
            acc2.w += a2.x*b0.w + a2.y*b1.w + a2.z*b2.w + a2.w*b3.w;
            acc3.x += a3.x*b0.x + a3.y*b1.x + a3.z*b2.x + a3.w*b3.x;
            acc3.y += a3.x*b0.y + a3.y*b1.y + a3.z*b2.y + a3.w*b3.y;
            acc3.z += a3.x*b0.z + a3.y*b1.z + a3.z*b2.z + a3.w*b3.z;
            acc3.w += a3.x*b0.w + a3.y*b1.w + a3.z*b2.w + a3.w*b3.w;
        }
        __syncthreads();
    }
    // store: cg<20 -> xl col cg4 ; else xr col cg4-80
    float* obase; int oc;
    if (cg < 20) { obase = xl; oc = cg4; } else { obase = xr; oc = cg4 - 80; }
    if (nd[0] < N_NODES) *(float4*)(obase + (size_t)nd[0] * H1 + oc) = acc0;
    if (nd[1] < N_NODES) *(float4*)(obase + (size_t)nd[1] * H1 + oc) = acc1;
    if (nd[2] < N_NODES) *(float4*)(obase + (size_t)nd[2] * H1 + oc) = acc2;
    if (nd[3] < N_NODES) *(float4*)(obase + (size_t)nd[3] * H1 + oc) = acc3;
}

// ---- layer1 aggregate: per (node,head) online softmax over CSR edges ----
__global__ void k_agg1(const int* __restrict__ start, const int* __restrict__ cnt,
                       const int* __restrict__ csr_src,
                       const float* __restrict__ xl, const float* __restrict__ xr,
                       const float* __restrict__ att, const float* __restrict__ b1,
                       float* __restrict__ h1) {
    int idx = blockIdx.x * blockDim.x + threadIdx.x;
    if (idx >= N_NODES * HEADS) return;
    int n = idx / HEADS, h = idx % HEADS;
    const float4* xrp = (const float4*)(xr + (size_t)n * H1 + h * DH);
    float4 r0 = xrp[0], r1 = xrp[1];
    const float4* atp = (const float4*)(att + h * DH);
    float4 t0 = atp[0], t1 = atp[1];
    float m = -__builtin_inff(), den = 0.f;
    float4 ac0 = {0.f,0.f,0.f,0.f}, ac1 = {0.f,0.f,0.f,0.f};
    int p0 = start[n], p1 = p0 + cnt[n];
    for (int p = p0; p < p1; ++p) {
        int s = csr_src[p];
        const float4* ap = (const float4*)(xl + (size_t)s * H1 + h * DH);
        float4 a0 = ap[0], a1 = ap[1];
        float lg = t0.x * lrelu(a0.x + r0.x) + t0.y * lrelu(a0.y + r0.y)
                 + t0.z * lrelu(a0.z + r0.z) + t0.w * lrelu(a0.w + r0.w)
                 + t1.x * lrelu(a1.x + r1.x) + t1.y * lrelu(a1.y + r1.y)
                 + t1.z * lrelu(a1.z + r1.z) + t1.w * lrelu(a1.w + r1.w);
        // one-exp online softmax: either the rescale or the new term is exp(0)=1
        float dd = lg - m;                 // first iter: +inf
        bool up = dd > 0.f;
        float e = __expf(up ? -dd : dd);   // exp(-|dd|); first iter -> 0
        float sc = up ? e : 1.f;
        float ex = up ? 1.f : e;
        if (up) m = lg;
        den = den * sc + ex;
        ac0.x = ac0.x * sc + ex * a0.x;
        ac0.y = ac0.y * sc + ex * a0.y;
        ac0.z = ac0.z * sc + ex * a0.z;
        ac0.w = ac0.w * sc + ex * a0.w;
        ac1.x = ac1.x * sc + ex * a1.x;
        ac1.y = ac1.y * sc + ex * a1.y;
        ac1.z = ac1.z * sc + ex * a1.z;
        ac1.w = ac1.w * sc + ex * a1.w;
    }
    float inv = 1.f / den;
    const float4* bp = (const float4*)(b1 + h * DH);
    float4 b0 = bp[0], b1v = bp[1];
    float4 o0, o1;
    o0.x = fmaxf(ac0.x * inv + b0.x, 0.f);
    o0.y = fmaxf(ac0.y * inv + b0.y, 0.f);
    o0.z = fmaxf(ac0.z * inv + b0.z, 0.f);
    o0.w = fmaxf(ac0.w * inv + b0.w, 0.f);
    o1.x = fmaxf(ac1.x * inv + b1v.x, 0.f);
    o1.y = fmaxf(ac1.y * inv + b1v.y, 0.f);
    o1.z = fmaxf(ac1.z * inv + b1v.z, 0.f);
    o1.w = fmaxf(ac1.w * inv + b1v.w, 0.f);
    float4* op = (float4*)(h1 + (size_t)n * H1 + h * DH);
    op[0] = o0; op[1] = o1;
}

// ---- layer2 GEMM: yl = h1@W2l, yr = h1@W2r (4 outputs / thread) ---------
__global__ void k_gemm2(const float* __restrict__ h1, const float* __restrict__ Wl,
                        const float* __restrict__ Wr, float* __restrict__ yl,
                        float* __restrict__ yr) {
    int idx = blockIdx.x * blockDim.x + threadIdx.x;
    if (idx >= N_NODES * 8) return;
    int n = idx / 8, g = idx % 8;
    const float* W; float* o; int cc;
    if (g < 4) { W = Wl; o = yl; cc = g * 4; }
    else       { W = Wr; o = yr; cc = (g - 4) * 4; }
    const float4* hrow = (const float4*)(h1 + (size_t)n * H1);
    float4 acc = {0.f, 0.f, 0.f, 0.f};
#pragma unroll 5
    for (int k4 = 0; k4 < H1 / 4; ++k4) {
        float4 hv = hrow[k4];
        int k = k4 * 4;
        float4 w0 = *(const float4*)(W + (size_t)(k + 0) * FOUT + cc);
        float4 w1 = *(const float4*)(W + (size_t)(k + 1) * FOUT + cc);
        float4 w2 = *(const float4*)(W + (size_t)(k + 2) * FOUT + cc);
        float4 w3 = *(const float4*)(W + (size_t)(k + 3) * FOUT + cc);
        acc.x += hv.x * w0.x + hv.y * w1.x + hv.z * w2.x + hv.w * w3.x;
        acc.y += hv.x * w0.y + hv.y * w1.y + hv.z * w2.y + hv.w * w3.y;
        acc.z += hv.x * w0.z + hv.y * w1.z + hv.z * w2.z + hv.w * w3.z;
        acc.w += hv.x * w0.w + hv.y * w1.w + hv.z * w2.w + hv.w * w3.w;
    }
    *(float4*)(o + (size_t)n * FOUT + cc) = acc;
}

// ---- layer2 aggregate: lane-quad per node, online softmax ---------------
__global__ void k_agg2(const int* __restrict__ start, const int* __restrict__ cnt,
                       const int* __restrict__ csr_src,
                       const float* __restrict__ yl, const float* __restrict__ yr,
                       const float* __restrict__ att, const float* __restrict__ b2,
                       float* __restrict__ out) {
    int idx = blockIdx.x * blockDim.x + threadIdx.x;
    if (idx >= N_NODES * 4) return;
    int n = idx >> 2, q = idx & 3;
    float4 r = ((const float4*)(yr + (size_t)n * FOUT))[q];
    float4 t = ((const float4*)att)[q];
    float m = -__builtin_inff(), den = 0.f;
    float4 acc = {0.f, 0.f, 0.f, 0.f};
    int p0 = start[n], p1 = p0 + cnt[n];
    for (int p = p0; p < p1; ++p) {
        int s = csr_src[p];
        float4 a = ((const float4*)(yl + (size_t)s * FOUT))[q];
        float part = t.x * lrelu(a.x + r.x) + t.y * lrelu(a.y + r.y)
                   + t.z * lrelu(a.z + r.z) + t.w * lrelu(a.w + r.w);
        part += __shfl_xor(part, 1);
        part += __shfl_xor(part, 2);   // full 16-dim logit in all 4 lanes
        float dd = part - m;
        bool up = dd > 0.f;
        float e = __expf(up ? -dd : dd);
        float sc = up ? e : 1.f;
        float ex = up ? 1.f : e;
        if (up) m = part;
        den = den * sc + ex;
        acc.x = acc.x * sc + ex * a.x;
        acc.y = acc.y * sc + ex * a.y;
        acc.z = acc.z * sc + ex * a.z;
        acc.w = acc.w * sc + ex * a.w;
    }
    float inv = 1.f / den;
    float4 bb = ((const float4*)b2)[q];
    float4 o = {acc.x * inv + bb.x, acc.y * inv + bb.y,
                acc.z * inv + bb.z, acc.w * inv + bb.w};
    ((float4*)(out + (size_t)n * FOUT))[q] = o;
}

extern "C" void kernel_launch(void* const* d_in, const int* in_sizes, int n_in,
                              void* d_out, int out_size, void* d_ws, size_t ws_size,
                              hipStream_t stream) {
    const float* x    = (const float*)d_in[0];
    const int*   ei   = (const int*)d_in[1];
    const float* W1l  = (const float*)d_in[2];
    const float* W1r  = (const float*)d_in[3];
    const float* att1 = (const float*)d_in[4];
    const float* b1   = (const float*)d_in[5];
    const float* W2l  = (const float*)d_in[6];
    const float* W2r  = (const float*)d_in[7];
    const float* att2 = (const float*)d_in[8];
    const float* b2   = (const float*)d_in[9];

    float* ws = (float*)d_ws;
    float* xl = ws;                 // 4,000,000 f
    float* xr = ws +  4000000;      // 4,000,000 f
    float* h1 = ws +  8000000;      // 4,000,000 f
    float* yl = ws + 12000000;      //   800,000 f
    float* yr = ws + 12800000;      //   800,000 f
    int* cnt     = (int*)(ws + 13600000);  //    50,000 i
    int* start   = cnt + 50000;            //    50,000 i
    int* cursor  = start + 50000;          //    50,000 i
    int* counter = cursor + 50000;         //         1 i
    int* csr_src = counter + 1;            //   850,000 i
    float* out = (float*)d_out;

    const int B = 256;
    // CSR build (counting sort by dst; bucket order from wave-batched atomics)
    k_zero <<<(N_NODES + B - 1) / B, B, 0, stream>>>(cnt, counter);
    k_count<<<(E_TOT + B - 1) / B, B, 0, stream>>>(ei, cnt);
    k_start<<<(N_NODES + B - 1) / B, B, 0, stream>>>(cnt, counter, start, cursor);
    k_fill <<<(E_TOT + B - 1) / B, B, 0, stream>>>(ei, cursor, csr_src);
    // layer 1
    k_gemm1t<<<(N_NODES + GN - 1) / GN, 320, 0, stream>>>(x, W1l, W1r, xl, xr);
    k_agg1 <<<(N_NODES * HEADS + B - 1) / B, B, 0, stream>>>(start, cnt, csr_src, xl, xr, att1, b1, h1);
    // layer 2
    k_gemm2<<<(N_NODES * 8 + B - 1) / B, B, 0, stream>>>(h1, W2l, W2r, yl, yr);
    k_agg2 <<<(N_NODES * 4 + B - 1) / B, B, 0, stream>>>(start, cnt, csr_src, yl, yr, att2, b2, out);
}